// Round 14
// baseline (60.887 us; speedup 1.0000x reference)
//
#include <hip/hip_runtime.h>
#include <math.h>

typedef float f32x4 __attribute__((ext_vector_type(4)));
typedef _Float16 f16;
typedef f16 f16x8 __attribute__((ext_vector_type(8)));
typedef unsigned int u32;
typedef u32 u32x2 __attribute__((ext_vector_type(2)));

#define BB 4096
#define TT 200
#define DD 32
#define H1 80
#define H2 40
#define SLAB_W 104     // f16 per slab row: 96 used + 8 pad -> 208B stride
#define LOG2E 1.44269504f

// pre-arranged tables (pack_kernel): per-lane-contiguous, pre-scaled by -log2e
__device__ __align__(16) float g_wqt[DD * DD];        // [col][e] = Wq[e][col]
__device__ __align__(16) float g_act[H1 * DD];        // [c][d] = -log2e*(A+C)[d][c]
__device__ __align__(16) float g_bcf[5 * 64 * 8];     // [n][l][e] = -log2e*(B-C)
__device__ __align__(16) float g_df [5 * 64 * 8];     // [n][l][e] = -log2e*D
__device__ __align__(16) f16   g_w2h[9 * 64 * 8];     // -log2e*W2 frags [kt*3+n][l][e]

__device__ __forceinline__ float exp2_raw(float x) {  // v_exp_f32 = 2^x
    float r;
    asm("v_exp_f32 %0, %1" : "=v"(r) : "v"(x));
    return r;
}
__device__ __forceinline__ float sig_pre(float a) {   // a = -log2e*z -> sigmoid(z)
    return __builtin_amdgcn_rcpf(1.f + exp2_raw(a));
}

__global__ void pack_kernel(const float* __restrict__ W1, const float* __restrict__ W2,
                            const float* __restrict__ Wq) {
    int idx = blockIdx.x * 256 + threadIdx.x;           // 13312 total = 52 blocks
    if (idx < DD * DD) {
        int col = idx / DD, e = idx % DD;
        g_wqt[idx] = Wq[e * DD + col];
        return;
    }
    idx -= DD * DD;
    if (idx < H1 * DD) {
        int c = idx / DD, d = idx % DD;
        g_act[idx] = -LOG2E * (W1[d * H1 + c] + W1[(64 + d) * H1 + c]);
        return;
    }
    idx -= H1 * DD;
    if (idx < 5 * 64 * 8) {
        int e = idx & 7, l = (idx >> 3) & 63, n = idx >> 9;
        int kidx = (l >> 4) * 8 + e;
        int j = n * 16 + (l & 15);
        g_bcf[idx] = -LOG2E * (W1[(32 + kidx) * H1 + j] - W1[(64 + kidx) * H1 + j]);
        g_df [idx] = -LOG2E * W1[(96 + kidx) * H1 + j];
        return;
    }
    idx -= 5 * 64 * 8;
    if (idx < 9 * 64 * 8) {
        int e = idx & 7, l = (idx >> 3) & 63, g = idx >> 9;
        int kt = g / 3, n = g % 3;
        int j   = kt * 32 + (l >> 4) * 8 + e;
        int col = n * 16 + (l & 15);
        float v = (j < H1 && col < H2) ? W2[j * H2 + col] : 0.f;
        g_w2h[idx] = (f16)(-LOG2E * v);
    }
}

// R14: TWO waves per row (even/odd tiles), grid 2048 = 8 blocks/CU target.
// Register pressure engineered <= ~64 (the m69 occupancy cliff): W2 frags read
// from L2-hot global per kt; u/b2/Wf in tiny LDS tables read per tile; k loaded
// JIT; mask loaded post-loop. NO min-waves launch_bounds (R5: untrustworthy cap).
// Validated model: R10 = P + L = 48.2, R11 = 2(P + L/2) = 58.6 with P=9.6 L=38.6;
// full residency here predicts P + L/2 ~ 29us.
__global__ __launch_bounds__(256) void din_mfma(
    const float* __restrict__ q, const float* __restrict__ k, const int* __restrict__ mask,
    const float* __restrict__ bq, const float* __restrict__ alpha,
    const float* __restrict__ b1, const float* __restrict__ b2, const float* __restrict__ Wf,
    float* __restrict__ out)
{
    const int tid = threadIdx.x;
    const int wid = tid >> 6, l = tid & 63;
    const int l15 = l & 15, lg4 = l >> 4;
    const int r   = wid >> 1, s = wid & 1;        // row-in-block, tile-parity
    const int b   = (blockIdx.x << 1) | r;

    __shared__ __align__(16) f16   slab[4][16][SLAB_W];   // per-wave slab
    __shared__ __align__(16) float qp_s[2][DD];
    __shared__ __align__(16) float u_s[2][H1];
    __shared__ __align__(16) float b2t[48], wft[48];
    __shared__ __align__(16) float lgt[2][208];

    // b2'/wf' tables (48 = 3n x 4lg4 x 4e, index == H2 col; pad cols -> 0)
    if (tid < 48) {
        b2t[tid] = tid < H2 ? -LOG2E * b2[tid] : 0.f;
        wft[tid] = tid < H2 ? LOG2E * Wf[tid] : 0.f;
    }
    // qp by sub-wave 0 of each row (lanes 0..31): all 16B vector loads
    if (s == 0 && l < DD) {
        const f32x4* qv = (const f32x4*)(q + (size_t)b * DD);
        const f32x4* wv = (const f32x4*)(g_wqt + l * DD);
        float acc = bq[l];
        #pragma unroll
        for (int i = 0; i < 8; ++i) {
            f32x4 a = qv[i], w = wv[i];
            acc += (a[0] * w[0] + a[1] * w[1]) + (a[2] * w[2] + a[3] * w[3]);
        }
        float al = alpha[l];
        qp_s[r][l] = acc >= 0.f ? acc : al * acc;
    }
    // zero own slab pad cols j=80..95 (kt=2 reads them; W2 frags are 0 there)
    {
        u32* z0 = (u32*)slab[wid];                // 52 u32 per row
        #pragma unroll
        for (int i = 0; i < 2; ++i) {
            int idx = i * 64 + l;
            z0[(idx >> 3) * 52 + 40 + (idx & 7)] = 0u;
        }
    }

    __syncthreads();   // barrier 1: qp_s / b2t / wft visible

    // qp -> registers (prologue-transient)
    f32x4 qp4[8];
    #pragma unroll
    for (int j = 0; j < 8; ++j) qp4[j] = *(const f32x4*)(&qp_s[r][j * 4]);

    // u' (redundant per sub-wave; identical values -> benign)
    #pragma unroll
    for (int i = 0; i < 2; ++i) {
        int c = i * 64 + l;
        if (c < H1) {
            const f32x4* av = (const f32x4*)(g_act + c * DD);
            float acc = -LOG2E * b1[c];
            #pragma unroll
            for (int j = 0; j < 8; ++j) {
                f32x4 a = av[j], p = qp4[j];
                acc += (a[0] * p[0] + a[1] * p[1]) + (a[2] * p[2] + a[3] * p[3]);
            }
            u_s[r][c] = acc;
        }
    }
    // Bh frags (per wave, 20 VGPRs — the one big register block in the loop)
    f32x4 qpa = *(const f32x4*)(&qp_s[r][lg4 * 8]);
    f32x4 qpb = *(const f32x4*)(&qp_s[r][lg4 * 8 + 4]);
    f16x8 Bh[5];
    #pragma unroll
    for (int n = 0; n < 5; ++n) {
        const f32x4* bv = (const f32x4*)(g_bcf + (n * 64 + l) * 8);
        const f32x4* dv = (const f32x4*)(g_df  + (n * 64 + l) * 8);
        f32x4 b0 = bv[0], b1v = bv[1], d0 = dv[0], d1 = dv[1];
        #pragma unroll
        for (int e = 0; e < 4; ++e) {
            Bh[n][e]     = (f16)(b0[e]  + qpa[e] * d0[e]);
            Bh[n][e + 4] = (f16)(b1v[e] + qpb[e] * d1[e]);
        }
    }

    // ---- main loop: this sub-wave owns tiles m = s, s+2, ... ----
    const float* kb = k + (size_t)b * (TT * DD);
    f16 (*ws)[SLAB_W] = slab[wid];
    float* lg = lgt[r];

    // L1(m): k loaded JIT (TLP from 8 waves/SIMD covers the latency)
    auto l1 = [&](int m) {
        int t = m * 16 + l15; if (t > TT - 1) t = TT - 1;
        const f32x4* kr = (const f32x4*)(kb + t * DD + lg4 * 8);
        f32x4 x0 = kr[0], x1 = kr[1];
        f16x8 Ah;
        #pragma unroll
        for (int e = 0; e < 4; ++e) {
            Ah[e]     = (f16)x0[e];
            Ah[e + 4] = (f16)x1[e];
        }
        #pragma unroll
        for (int n = 0; n < 5; ++n) {
            int j0 = n * 16 + lg4 * 4;
            f32x4 acc = *(const f32x4*)(&u_s[r][j0]);     // u' from LDS
            acc = __builtin_amdgcn_mfma_f32_16x16x32_f16(Bh[n], Ah, acc, 0, 0, 0);
            auto p01 = __builtin_amdgcn_cvt_pkrtz(sig_pre(acc[0]), sig_pre(acc[1]));
            auto p23 = __builtin_amdgcn_cvt_pkrtz(sig_pre(acc[2]), sig_pre(acc[3]));
            u32x2 w;
            w[0] = __builtin_bit_cast(u32, p01);
            w[1] = __builtin_bit_cast(u32, p23);
            *(u32x2*)(&ws[l15][j0]) = w;
        }
    };

    // body(m): L2 on tile m (slab holds it; JIT sh + global W2 frags), then L1(m+2)
    auto body = [&](int m) {
        f32x4 a0 = {0.f,0.f,0.f,0.f}, a1 = {0.f,0.f,0.f,0.f}, a2 = {0.f,0.f,0.f,0.f};
        #pragma unroll
        for (int kt = 0; kt < 3; ++kt) {
            f16x8 sh = *(const f16x8*)(&ws[l15][kt * 32 + lg4 * 8]);
            f16x8 w0 = *(const f16x8*)(g_w2h + ((kt * 3 + 0) * 64 + l) * 8);
            f16x8 w1 = *(const f16x8*)(g_w2h + ((kt * 3 + 1) * 64 + l) * 8);
            f16x8 w2 = *(const f16x8*)(g_w2h + ((kt * 3 + 2) * 64 + l) * 8);
            a0 = __builtin_amdgcn_mfma_f32_16x16x32_f16(w0, sh, a0, 0, 0, 0);
            a1 = __builtin_amdgcn_mfma_f32_16x16x32_f16(w1, sh, a1, 0, 0, 0);
            a2 = __builtin_amdgcn_mfma_f32_16x16x32_f16(w2, sh, a2, 0, 0, 0);
        }
        float pn[3];
        #pragma unroll
        for (int n = 0; n < 3; ++n) {
            f32x4 av = (n == 0) ? a0 : (n == 1) ? a1 : a2;
            f32x4 bqv = *(const f32x4*)(&b2t[n * 16 + lg4 * 4]);
            f32x4 wqv = *(const f32x4*)(&wft[n * 16 + lg4 * 4]);
            float t0 = wqv[0] * sig_pre(av[0] + bqv[0]);
            float t1 = wqv[1] * sig_pre(av[1] + bqv[1]);
            float t2 = wqv[2] * sig_pre(av[2] + bqv[2]);
            float t3 = wqv[3] * sig_pre(av[3] + bqv[3]);
            pn[n] = (t0 + t1) + (t2 + t3);
        }
        float p = (pn[0] + pn[1]) + pn[2];
        p += __shfl_xor(p, 16);
        p += __shfl_xor(p, 32);
        if (l < 16) lg[m * 16 + l15] = p;
        if (m + 2 < 13) l1(m + 2);
    };

    l1(s);
    for (int m = s; m < 13; m += 2) body(m);

    // mask loads issued post-loop (live only across the final barrier)
    const int* mrow = mask + (size_t)b * TT;
    int mk0 = mrow[l];
    int mk1 = mrow[64 + l];
    int mk2 = mrow[128 + l];
    int mk3 = (l < 8) ? mrow[192 + l] : 1;

    __syncthreads();   // barrier 2: lgt complete from both sub-waves

    // ---- masked softmax over t<200 (base-2; logits pre-scaled by log2e) ----
    const float NEG = -4294967295.0f;
    float v0 = lg[l];        if (mk0 == 0) v0 = NEG;
    float v1 = lg[64 + l];   if (mk1 == 0) v1 = NEG;
    float v2 = lg[128 + l];  if (mk2 == 0) v2 = NEG;
    float v3 = -8589934590.0f;
    if (l < 8) { v3 = lg[192 + l]; if (mk3 == 0) v3 = NEG; }

    float mx = fmaxf(fmaxf(v0, v1), fmaxf(v2, v3));
    #pragma unroll
    for (int off = 32; off; off >>= 1) mx = fmaxf(mx, __shfl_xor(mx, off));

    float e0 = exp2_raw(v0 - mx), e1 = exp2_raw(v1 - mx);
    float e2 = exp2_raw(v2 - mx), e3 = exp2_raw(v3 - mx);
    float ssum = (e0 + e1) + (e2 + e3);
    #pragma unroll
    for (int off = 32; off; off >>= 1) ssum += __shfl_xor(ssum, off);

    float* orow = out + (size_t)b * TT;
    if (s == 0) {
        orow[l]      = e0 / ssum;
        orow[64 + l] = e1 / ssum;
    } else {
        orow[128 + l] = e2 / ssum;
        if (l < 8) orow[192 + l] = e3 / ssum;
    }
}

extern "C" void kernel_launch(void* const* d_in, const int* in_sizes, int n_in,
                              void* d_out, int out_size, void* d_ws, size_t ws_size,
                              hipStream_t stream) {
    const float* q     = (const float*)d_in[0];
    const float* k     = (const float*)d_in[1];
    // d_in[2] = v : unused by the reference output
    const int*   mask  = (const int*)d_in[3];
    const float* Wq    = (const float*)d_in[4];
    const float* bq    = (const float*)d_in[5];
    const float* alpha = (const float*)d_in[6];
    const float* W1    = (const float*)d_in[7];
    const float* b1    = (const float*)d_in[8];
    const float* W2    = (const float*)d_in[9];
    const float* b2    = (const float*)d_in[10];
    const float* Wf    = (const float*)d_in[11];
    // d_in[12] = bf : dropped (softmax is shift-invariant, incl. all-masked rows)
    float* out = (float*)d_out;

    hipLaunchKernelGGL(pack_kernel, dim3(52), dim3(256), 0, stream, W1, W2, Wq);
    hipLaunchKernelGGL(din_mfma, dim3(BB / 2), dim3(256), 0, stream,
                       q, k, mask, bq, alpha, b1, b2, Wf, out);
}